// Round 2
// baseline (838.638 us; speedup 1.0000x reference)
//
#include <hip/hip_runtime.h>
#include <math.h>

#define B_ 16
#define NSUP_ 4096
#define NQ_ 4096
#define D_ 512
#define C_ 128
#define NCHP 4
#define ROWS (NSUP_/NCHP)      // 1024 support rows per partial block
#define MARGIN 0.0625f         // f32 screen gap margin (worst-case f32 err ~2.5e-3, 25x safety)

// ---------------- K1a: prototype partial sums (deterministic f64) ----------------
// grid: B_*16cg*NCHP = 1024 blocks, 256 threads. Block: 8 classes, ROWS support rows.
__global__ __launch_bounds__(256) void proto_partial_kernel(
    const float* __restrict__ sup, const int* __restrict__ tgt,
    double* __restrict__ part_sums, int* __restrict__ part_cnt)
{
    __shared__ int    lt[ROWS];       // 4 KB
    __shared__ double acc[8][D_];     // 32 KB
    int blk = blockIdx.x;
    int b   = blk >> 6;
    int rem = blk & 63;
    int cg  = (rem >> 2) * 8;
    int ch  = rem & 3;
    int n0  = ch * ROWS;
    int tid = threadIdx.x;
    int d0 = tid, d1 = tid + 256;

    for (int i = tid; i < ROWS; i += 256) lt[i] = tgt[b*NSUP_ + n0 + i];
    #pragma unroll
    for (int k = 0; k < 8; k++) { acc[k][d0] = 0.0; acc[k][d1] = 0.0; }
    __syncthreads();

    const float* e = sup + ((size_t)b*NSUP_ + n0)*D_;
    int mycnt = 0;
    for (int n = 0; n < ROWS; n++) {
        int idx = lt[n] - cg;              // block-uniform branch
        if ((unsigned)idx < 8u) {
            const float* row = e + (size_t)n*D_;
            acc[idx][d0] += (double)row[d0];
            acc[idx][d1] += (double)row[d1];
            if (tid == idx) mycnt++;
        }
    }
    __syncthreads();
    double* po = part_sums + (size_t)blk * 8 * D_;
    #pragma unroll
    for (int k = 0; k < 8; k++) {
        po[(size_t)k*D_ + d0] = acc[k][d0];
        po[(size_t)k*D_ + d1] = acc[k][d1];
    }
    if (tid < 8) part_cnt[blk*8 + tid] = mycnt;
}

// ---------------- K1b: reduce partials -> protos (f64 transposed + f32) + p_sq ----------------
// grid: B_*C_ = 2048 blocks, 256 threads.
__global__ __launch_bounds__(256) void proto_reduce_kernel(
    const double* __restrict__ part_sums, const int* __restrict__ part_cnt,
    double* __restrict__ pT64, float* __restrict__ pf32,
    double* __restrict__ psq64, float* __restrict__ psq32,
    int* __restrict__ flag_count, int* __restrict__ acc_delta)
{
    __shared__ double redbuf[256];
    int g = blockIdx.x;
    int b = g >> 7;
    int c = g & 127;
    int cg8 = c >> 3, cls = c & 7;
    int tid = threadIdx.x;
    int d0 = tid, d1 = tid + 256;

    double s0 = 0.0, s1 = 0.0; int cnt = 0;
    #pragma unroll
    for (int ch = 0; ch < NCHP; ch++) {
        int pblk = (b*16 + cg8)*NCHP + ch;
        const double* ps = part_sums + ((size_t)pblk*8 + cls)*D_;
        s0 += ps[d0]; s1 += ps[d1];
        cnt += part_cnt[pblk*8 + cls];
    }
    double cw = (double)(cnt > 1 ? cnt : 1);
    double p0 = s0 / cw, p1 = s1 / cw;
    pT64[((size_t)b*D_ + d0)*C_ + c] = p0;
    pT64[((size_t)b*D_ + d1)*C_ + c] = p1;
    pf32[((size_t)(b*C_ + c))*D_ + d0] = (float)p0;
    pf32[((size_t)(b*C_ + c))*D_ + d1] = (float)p1;
    redbuf[tid] = p0*p0 + p1*p1;
    __syncthreads();
    for (int s = 128; s > 0; s >>= 1) {
        if (tid < s) redbuf[tid] += redbuf[tid + s];
        __syncthreads();
    }
    if (tid == 0) {
        psq64[g] = redbuf[0];
        psq32[g] = (float)redbuf[0];
        if (g == 0) { *flag_count = 0; *acc_delta = 0; }
    }
}

// ---------------- K2: f32 screening GEMM + argmin/top2 + lse + nll ----------------
// grid: B_ * (NQ_/32) = 2048 blocks, 256 threads (4 waves, 8 queries/wave).
// Lane owns classes (lane, lane+64); accumulates full 512-dim dot per query in regs.
__global__ __launch_bounds__(256) void screen_kernel(
    const float* __restrict__ qry, const int* __restrict__ qtgt,
    const float* __restrict__ pf32, const float* __restrict__ psq32,
    float* __restrict__ out_pred, double* __restrict__ blk_loss,
    float* __restrict__ blk_acc, int* __restrict__ flags, int* __restrict__ flag_count)
{
    __shared__ float ldsP[C_][66];     // [class][dl], pad 66 -> conflict-free b64: 33792 B
    __shared__ float ldsQ[4][8][64];   // per-wave 8 queries x 64-dim chunk: 8192 B
    __shared__ double wl[4];
    __shared__ float  wa[4];

    int blk  = blockIdx.x;
    int b    = blk >> 7;
    int qb   = (blk & 127) * 32;
    int tid  = threadIdx.x;
    int wave = tid >> 6, lane = tid & 63;
    int q0   = qb + wave * 8;

    const float* qbase = qry + ((size_t)b*NQ_ + q0)*D_;

    // exact-ish per-query ||q||^2 in f64 (read from global; re-read in staging hits cache)
    double qsq[8];
    #pragma unroll
    for (int j = 0; j < 8; j++) {
        const float* qp = qbase + (size_t)j*D_;
        double ss = 0.0;
        #pragma unroll
        for (int k = 0; k < 8; k++) {
            double v = (double)qp[lane + 64*k];
            ss = fma(v, v, ss);
        }
        for (int off = 32; off; off >>= 1) ss += __shfl_xor(ss, off, 64);
        qsq[j] = ss;
    }

    float acc0[8] = {0,0,0,0,0,0,0,0};
    float acc1[8] = {0,0,0,0,0,0,0,0};
    const float* pb32 = pf32 + (size_t)b*C_*D_;

    for (int ch = 0; ch < 8; ch++) {
        __syncthreads();
        for (int i = tid; i < C_*64; i += 256) {
            int c = i >> 6, dl = i & 63;
            ldsP[c][dl] = pb32[(size_t)c*D_ + ch*64 + dl];
        }
        #pragma unroll
        for (int j = 0; j < 8; j++)
            ldsQ[wave][j][lane] = qbase[(size_t)j*D_ + ch*64 + lane];
        __syncthreads();

        #pragma unroll 4
        for (int dl = 0; dl < 64; dl += 2) {
            float2 p0 = *(const float2*)&ldsP[lane][dl];
            float2 p1 = *(const float2*)&ldsP[lane + 64][dl];
            #pragma unroll
            for (int j = 0; j < 8; j++) {
                float2 qv = *(const float2*)&ldsQ[wave][j][dl];
                acc0[j] = fmaf(p0.x, qv.x, acc0[j]);
                acc0[j] = fmaf(p0.y, qv.y, acc0[j]);
                acc1[j] = fmaf(p1.x, qv.x, acc1[j]);
                acc1[j] = fmaf(p1.y, qv.y, acc1[j]);
            }
        }
    }

    float ps0 = psq32[b*C_ + lane];
    float ps1 = psq32[b*C_ + lane + 64];
    double wloss = 0.0; float wacc = 0.0f;

    for (int j = 0; j < 8; j++) {
        float qs  = (float)qsq[j];
        float df0 = ps0 + qs - 2.0f*acc0[j];
        float df1 = ps1 + qs - 2.0f*acc1[j];

        // top-2 (best dist+class, second-best dist) butterfly; first-index tie-break
        float b1, b2; int c1;
        if (df1 < df0) { b1 = df1; c1 = lane + 64; b2 = df0; }
        else           { b1 = df0; c1 = lane;      b2 = df1; }
        for (int off = 32; off; off >>= 1) {
            float o1 = __shfl_xor(b1, off, 64);
            int   oc = __shfl_xor(c1, off, 64);
            float o2 = __shfl_xor(b2, off, 64);
            float n2 = fminf(fmaxf(b1, o1), fminf(b2, o2));
            if (o1 < b1 || (o1 == b1 && oc < c1)) { b1 = o1; c1 = oc; }
            b2 = n2;
        }

        // logsumexp of -dist over 128 classes
        float nd0 = -df0, nd1 = -df1;
        float lm = fmaxf(nd0, nd1);
        float ls = __expf(nd0 - lm) + __expf(nd1 - lm);
        for (int off = 32; off; off >>= 1) {
            float om = __shfl_xor(lm, off, 64);
            float os = __shfl_xor(ls, off, 64);
            float nm = fmaxf(lm, om);
            ls = ls * __expf(lm - nm) + os * __expf(om - nm);
            lm = nm;
        }

        int tq = qtgt[b*NQ_ + q0 + j];
        float cand = (tq & 64) ? df1 : df0;
        float dt = __shfl(cand, tq & 63, 64);
        wloss += (double)(dt + lm) + (double)logf(ls);
        wacc  += (c1 == tq) ? 1.0f : 0.0f;

        if (lane == 0) {
            int gq = b*NQ_ + q0 + j;
            out_pred[gq] = (float)c1;
            if (b2 - b1 < MARGIN) {
                int pos = atomicAdd(flag_count, 1);
                flags[pos] = gq;
            }
        }
    }

    if (lane == 0) { wl[wave] = wloss; wa[wave] = wacc; }
    __syncthreads();
    if (tid == 0) {
        blk_loss[blk] = wl[0] + wl[1] + wl[2] + wl[3];
        blk_acc[blk]  = wa[0] + wa[1] + wa[2] + wa[3];
    }
}

// ---------------- K3: f64 exact rescue for near-tied queries ----------------
// grid: 256 blocks x 256 threads; block handles one flagged query at a time.
__global__ __launch_bounds__(256) void rescue_kernel(
    const float* __restrict__ qry, const int* __restrict__ qtgt,
    const double* __restrict__ pT64, const double* __restrict__ psq64,
    const int* __restrict__ flags, const int* __restrict__ flag_count,
    float* __restrict__ out_pred, int* __restrict__ acc_delta)
{
    __shared__ float  qbuf[D_];
    __shared__ double qsqred[256];
    __shared__ double partial[256];
    __shared__ double dists[C_];
    int tid = threadIdx.x;
    int cnt = *flag_count;

    for (int f = blockIdx.x; f < cnt; f += 256) {
        int gq = flags[f];
        int b  = gq >> 12;
        const float* qp = qry + (size_t)gq * D_;

        double ss = 0.0;
        #pragma unroll
        for (int k = 0; k < 2; k++) {
            int d = tid + 256*k;
            float v = qp[d];
            qbuf[d] = v;
            ss = fma((double)v, (double)v, ss);
        }
        qsqred[tid] = ss;
        __syncthreads();
        for (int s = 128; s > 0; s >>= 1) {
            if (tid < s) qsqred[tid] += qsqred[tid + s];
            __syncthreads();
        }
        double qsq = qsqred[0];

        int c = tid & 127, part = tid >> 7;
        const double* pTb = pT64 + (size_t)b * D_ * C_;
        double acc = 0.0;
        for (int d = part*256; d < part*256 + 256; d++)
            acc = fma(pTb[(size_t)d*C_ + c], (double)qbuf[d], acc);
        partial[tid] = acc;
        __syncthreads();
        if (tid < C_)
            dists[tid] = psq64[b*C_ + tid] + qsq - 2.0*(partial[tid] + partial[tid + 128]);
        __syncthreads();

        if (tid < 64) {
            double x0 = dists[tid], x1 = dists[tid + 64];
            double bd; int bc;
            if (x1 < x0) { bd = x1; bc = tid + 64; } else { bd = x0; bc = tid; }
            for (int off = 32; off; off >>= 1) {
                double od = __shfl_xor(bd, off, 64);
                int    oc = __shfl_xor(bc, off, 64);
                if (od < bd || (od == bd && oc < bc)) { bd = od; bc = oc; }
            }
            if (tid == 0) {
                int tq = qtgt[gq];
                int oldc = (int)out_pred[gq];
                if (oldc != bc) {
                    out_pred[gq] = (float)bc;
                    int delta = ((bc == tq) ? 1 : 0) - ((oldc == tq) ? 1 : 0);
                    if (delta) atomicAdd(acc_delta, delta);
                }
            }
        }
        __syncthreads();
    }
}

// ---------------- K4: finalize loss + accuracy ----------------
__global__ __launch_bounds__(256) void finalize_kernel(
    const double* __restrict__ blk_loss, const float* __restrict__ blk_acc,
    const int* __restrict__ acc_delta, float* __restrict__ out)
{
    __shared__ double rl[256];
    __shared__ float  ra[256];
    int tid = threadIdx.x;
    double s = 0.0; float a = 0.0f;
    for (int i = tid; i < 2048; i += 256) { s += blk_loss[i]; a += blk_acc[i]; }
    rl[tid] = s; ra[tid] = a;
    __syncthreads();
    for (int st = 128; st; st >>= 1) {
        if (tid < st) { rl[tid] += rl[tid + st]; ra[tid] += ra[tid + st]; }
        __syncthreads();
    }
    if (tid == 0) {
        out[B_*NQ_    ] = (float)(rl[0] / (double)(B_*NQ_));
        out[B_*NQ_ + 1] = (ra[0] + (float)(*acc_delta)) / (float)(B_*NQ_);
    }
}

extern "C" void kernel_launch(void* const* d_in, const int* in_sizes, int n_in,
                              void* d_out, int out_size, void* d_ws, size_t ws_size,
                              hipStream_t stream) {
    const float* sup  = (const float*)d_in[0];
    const float* qry  = (const float*)d_in[1];
    const int*   stgt = (const int*)d_in[2];
    const int*   qtgt = (const int*)d_in[3];
    float* out = (float*)d_out;

    char* ws = (char*)d_ws;
    constexpr size_t O_PART  = 0;                            // 1024*8*512*8 = 32 MiB
    constexpr size_t O_PCNT  = O_PART  + (size_t)1024*8*512*8;   // 32 KiB
    constexpr size_t O_PT64  = O_PCNT  + (size_t)1024*8*4;       // 8 MiB
    constexpr size_t O_PF32  = O_PT64  + (size_t)B_*D_*C_*8;     // 4 MiB
    constexpr size_t O_PSQ64 = O_PF32  + (size_t)B_*C_*D_*4;     // 16 KiB
    constexpr size_t O_PSQ32 = O_PSQ64 + (size_t)B_*C_*8;        // 8 KiB
    constexpr size_t O_BLOSS = O_PSQ32 + (size_t)B_*C_*4;        // 16 KiB
    constexpr size_t O_BACC  = O_BLOSS + (size_t)2048*8;         // 8 KiB
    constexpr size_t O_FLAGS = O_BACC  + (size_t)2048*4;         // 256 KiB
    constexpr size_t O_CNTRS = O_FLAGS + (size_t)65536*4;        // 8 B

    double* part_sums = (double*)(ws + O_PART);
    int*    part_cnt  = (int*)   (ws + O_PCNT);
    double* pT64      = (double*)(ws + O_PT64);
    float*  pf32      = (float*) (ws + O_PF32);
    double* psq64     = (double*)(ws + O_PSQ64);
    float*  psq32     = (float*) (ws + O_PSQ32);
    double* blk_loss  = (double*)(ws + O_BLOSS);
    float*  blk_acc   = (float*) (ws + O_BACC);
    int*    flags     = (int*)   (ws + O_FLAGS);
    int*    flag_count= (int*)   (ws + O_CNTRS);
    int*    acc_delta = flag_count + 1;

    hipLaunchKernelGGL(proto_partial_kernel, dim3(1024), dim3(256), 0, stream,
                       sup, stgt, part_sums, part_cnt);
    hipLaunchKernelGGL(proto_reduce_kernel, dim3(2048), dim3(256), 0, stream,
                       part_sums, part_cnt, pT64, pf32, psq64, psq32, flag_count, acc_delta);
    hipLaunchKernelGGL(screen_kernel, dim3(2048), dim3(256), 0, stream,
                       qry, qtgt, pf32, psq32, out, blk_loss, blk_acc, flags, flag_count);
    hipLaunchKernelGGL(rescue_kernel, dim3(256), dim3(256), 0, stream,
                       qry, qtgt, pT64, psq64, flags, flag_count, out, acc_delta);
    hipLaunchKernelGGL(finalize_kernel, dim3(1), dim3(256), 0, stream,
                       blk_loss, blk_acc, acc_delta, out);
}

// Round 3
// 543.942 us; speedup vs baseline: 1.5418x; 1.5418x over previous
//
#include <hip/hip_runtime.h>
#include <math.h>

#define B_ 16
#define NSUP_ 4096
#define NQ_ 4096
#define D_ 512
#define C_ 128
#define NCHP 4
#define ROWS (NSUP_/NCHP)      // 1024 support rows per partial block
#define MARGIN 0.008f          // f32 gap error worst ~2e-4 (qsq cancels); 40x safety

// ---------------- K1a: prototype partial sums (deterministic f64) ----------------
// grid: B_*16cg*NCHP = 1024 blocks, 256 threads. Block: 8 classes, ROWS support rows.
__global__ __launch_bounds__(256) void proto_partial_kernel(
    const float* __restrict__ sup, const int* __restrict__ tgt,
    double* __restrict__ part_sums, int* __restrict__ part_cnt)
{
    __shared__ int    lt[ROWS];       // 4 KB
    __shared__ double acc[8][D_];     // 32 KB
    int blk = blockIdx.x;
    int b   = blk >> 6;
    int rem = blk & 63;
    int cg  = (rem >> 2) * 8;
    int ch  = rem & 3;
    int n0  = ch * ROWS;
    int tid = threadIdx.x;
    int d0 = tid, d1 = tid + 256;

    for (int i = tid; i < ROWS; i += 256) lt[i] = tgt[b*NSUP_ + n0 + i];
    #pragma unroll
    for (int k = 0; k < 8; k++) { acc[k][d0] = 0.0; acc[k][d1] = 0.0; }
    __syncthreads();

    const float* e = sup + ((size_t)b*NSUP_ + n0)*D_;
    int mycnt = 0;
    for (int n = 0; n < ROWS; n += 16) {
        int idx[16];
        #pragma unroll
        for (int u = 0; u < 16; u++) idx[u] = lt[n + u] - cg;   // 16 ds_reads batch -> 1 wait
        #pragma unroll
        for (int u = 0; u < 16; u++) {
            if ((unsigned)idx[u] < 8u) {                         // block-uniform branch
                const float* row = e + (size_t)(n + u)*D_;
                float v0 = row[d0], v1 = row[d1];
                acc[idx[u]][d0] += (double)v0;
                acc[idx[u]][d1] += (double)v1;
                if (tid == idx[u]) mycnt++;
            }
        }
    }
    __syncthreads();
    double* po = part_sums + (size_t)blk * 8 * D_;
    #pragma unroll
    for (int k = 0; k < 8; k++) {
        po[(size_t)k*D_ + d0] = acc[k][d0];
        po[(size_t)k*D_ + d1] = acc[k][d1];
    }
    if (tid < 8) part_cnt[blk*8 + tid] = mycnt;
}

// ---------------- K1b: reduce partials -> protos (f64 transposed + f32) + p_sq ----------------
// grid: B_*C_ = 2048 blocks, 256 threads.
__global__ __launch_bounds__(256) void proto_reduce_kernel(
    const double* __restrict__ part_sums, const int* __restrict__ part_cnt,
    double* __restrict__ pT64, float* __restrict__ pf32,
    double* __restrict__ psq64, float* __restrict__ psq32,
    int* __restrict__ flag_count, int* __restrict__ acc_delta)
{
    __shared__ double redbuf[256];
    int g = blockIdx.x;
    int b = g >> 7;
    int c = g & 127;
    int cg8 = c >> 3, cls = c & 7;
    int tid = threadIdx.x;
    int d0 = tid, d1 = tid + 256;

    double s0 = 0.0, s1 = 0.0; int cnt = 0;
    #pragma unroll
    for (int ch = 0; ch < NCHP; ch++) {
        int pblk = (b*16 + cg8)*NCHP + ch;
        const double* ps = part_sums + ((size_t)pblk*8 + cls)*D_;
        s0 += ps[d0]; s1 += ps[d1];
        cnt += part_cnt[pblk*8 + cls];
    }
    double cw = (double)(cnt > 1 ? cnt : 1);
    double p0 = s0 / cw, p1 = s1 / cw;
    pT64[((size_t)b*D_ + d0)*C_ + c] = p0;
    pT64[((size_t)b*D_ + d1)*C_ + c] = p1;
    pf32[((size_t)(b*C_ + c))*D_ + d0] = (float)p0;
    pf32[((size_t)(b*C_ + c))*D_ + d1] = (float)p1;
    redbuf[tid] = p0*p0 + p1*p1;
    __syncthreads();
    for (int s = 128; s > 0; s >>= 1) {
        if (tid < s) redbuf[tid] += redbuf[tid + s];
        __syncthreads();
    }
    if (tid == 0) {
        psq64[g] = redbuf[0];
        psq32[g] = (float)redbuf[0];
        if (g == 0) { *flag_count = 0; *acc_delta = 0; }
    }
}

// ---------------- K2: f32 screening GEMM + argmin/top2 + lse + nll ----------------
// grid: B_ * (NQ_/32) = 2048 blocks, 256 threads (4 waves, 8 queries/wave).
__global__ __launch_bounds__(256) void screen_kernel(
    const float* __restrict__ qry, const int* __restrict__ qtgt,
    const float* __restrict__ pf32, const float* __restrict__ psq32,
    float* __restrict__ out_pred, double* __restrict__ blk_loss,
    float* __restrict__ blk_acc, int* __restrict__ flags, int* __restrict__ flag_count)
{
    __shared__ float ldsP[C_][66];     // stride 66: 2-way bank alias (free), 8B-aligned rows
    __shared__ float ldsQ[4][8][64];   // per-wave 8 queries x 64-dim chunk
    __shared__ double wl[4];
    __shared__ float  wa[4];

    int blk  = blockIdx.x;
    int b    = blk >> 7;
    int qb   = (blk & 127) * 32;
    int tid  = threadIdx.x;
    int wave = tid >> 6, lane = tid & 63;
    int q0   = qb + wave * 8;

    const float* qbase = qry + ((size_t)b*NQ_ + q0)*D_;

    float acc0[8] = {0,0,0,0,0,0,0,0};
    float acc1[8] = {0,0,0,0,0,0,0,0};
    const float* pb32 = pf32 + (size_t)b*C_*D_;

    for (int ch = 0; ch < 8; ch++) {
        __syncthreads();
        for (int i = tid; i < C_*64; i += 256) {
            int c = i >> 6, dl = i & 63;
            ldsP[c][dl] = pb32[(size_t)c*D_ + ch*64 + dl];
        }
        #pragma unroll
        for (int j = 0; j < 8; j++)
            ldsQ[wave][j][lane] = qbase[(size_t)j*D_ + ch*64 + lane];
        __syncthreads();

        #pragma unroll 4
        for (int dl = 0; dl < 64; dl += 4) {
            float2 p0a = *(const float2*)&ldsP[lane][dl];
            float2 p0b = *(const float2*)&ldsP[lane][dl + 2];
            float2 p1a = *(const float2*)&ldsP[lane + 64][dl];
            float2 p1b = *(const float2*)&ldsP[lane + 64][dl + 2];
            #pragma unroll
            for (int j = 0; j < 8; j++) {
                float4 qv = *(const float4*)&ldsQ[wave][j][dl];
                acc0[j] = fmaf(p0a.x, qv.x, acc0[j]);
                acc0[j] = fmaf(p0a.y, qv.y, acc0[j]);
                acc0[j] = fmaf(p0b.x, qv.z, acc0[j]);
                acc0[j] = fmaf(p0b.y, qv.w, acc0[j]);
                acc1[j] = fmaf(p1a.x, qv.x, acc1[j]);
                acc1[j] = fmaf(p1a.y, qv.y, acc1[j]);
                acc1[j] = fmaf(p1b.x, qv.z, acc1[j]);
                acc1[j] = fmaf(p1b.y, qv.w, acc1[j]);
            }
        }
    }

    // per-query ||q||^2 in f64 (after main loop: short live range; q rows are cache-hot)
    double qsq[8];
    #pragma unroll
    for (int j = 0; j < 8; j++) {
        const float* qp = qbase + (size_t)j*D_;
        double ss = 0.0;
        #pragma unroll
        for (int k = 0; k < 8; k++) {
            double v = (double)qp[lane + 64*k];
            ss = fma(v, v, ss);
        }
        for (int off = 32; off; off >>= 1) ss += __shfl_xor(ss, off, 64);
        qsq[j] = ss;
    }

    float ps0 = psq32[b*C_ + lane];
    float ps1 = psq32[b*C_ + lane + 64];
    double wloss = 0.0; float wacc = 0.0f;

    for (int j = 0; j < 8; j++) {
        float qs  = (float)qsq[j];
        float df0 = ps0 + qs - 2.0f*acc0[j];
        float df1 = ps1 + qs - 2.0f*acc1[j];

        // top-2 butterfly (best dist+class, second-best dist); first-index tie-break
        float b1, b2; int c1;
        if (df1 < df0) { b1 = df1; c1 = lane + 64; b2 = df0; }
        else           { b1 = df0; c1 = lane;      b2 = df1; }
        for (int off = 32; off; off >>= 1) {
            float o1 = __shfl_xor(b1, off, 64);
            int   oc = __shfl_xor(c1, off, 64);
            float o2 = __shfl_xor(b2, off, 64);
            float n2 = fminf(fmaxf(b1, o1), fminf(b2, o2));
            if (o1 < b1 || (o1 == b1 && oc < c1)) { b1 = o1; c1 = oc; }
            b2 = n2;
        }

        // logsumexp of -dist over 128 classes
        float nd0 = -df0, nd1 = -df1;
        float lm = fmaxf(nd0, nd1);
        float ls = __expf(nd0 - lm) + __expf(nd1 - lm);
        for (int off = 32; off; off >>= 1) {
            float om = __shfl_xor(lm, off, 64);
            float os = __shfl_xor(ls, off, 64);
            float nm = fmaxf(lm, om);
            ls = ls * __expf(lm - nm) + os * __expf(om - nm);
            lm = nm;
        }

        int tq = qtgt[b*NQ_ + q0 + j];
        float cand = (tq & 64) ? df1 : df0;
        float dt = __shfl(cand, tq & 63, 64);
        wloss += (double)(dt + lm) + (double)logf(ls);
        wacc  += (c1 == tq) ? 1.0f : 0.0f;

        if (lane == 0) {
            int gq = b*NQ_ + q0 + j;
            out_pred[gq] = (float)c1;
            if (b2 - b1 < MARGIN) {
                int pos = atomicAdd(flag_count, 1);
                flags[pos] = gq;
            }
        }
    }

    if (lane == 0) { wl[wave] = wloss; wa[wave] = wacc; }
    __syncthreads();
    if (tid == 0) {
        blk_loss[blk] = wl[0] + wl[1] + wl[2] + wl[3];
        blk_acc[blk]  = wa[0] + wa[1] + wa[2] + wa[3];
    }
}

// ---------------- K3: f64 exact rescue, wave-per-query, lane-per-class ----------------
// grid: 256 blocks x 256 threads = 1024 waves; wave w handles flags[w], flags[w+1024], ...
__global__ __launch_bounds__(256) void rescue_kernel(
    const float* __restrict__ qry, const int* __restrict__ qtgt,
    const double* __restrict__ pT64, const double* __restrict__ psq64,
    const int* __restrict__ flags, const int* __restrict__ flag_count,
    float* __restrict__ out_pred, int* __restrict__ acc_delta)
{
    __shared__ float qs[4][D_];     // wave-private q stage (8 KB)
    int tid  = threadIdx.x;
    int wave = tid >> 6, lane = tid & 63;
    int cnt  = *flag_count;
    int gwid = blockIdx.x * 4 + wave;

    for (int f = gwid; f < cnt; f += 1024) {
        int gq = flags[f];
        int b  = gq >> 12;
        const float* qp = qry + (size_t)gq * D_;

        double qsq = 0.0;
        #pragma unroll
        for (int k = 0; k < 8; k++) {
            float v = qp[lane + 64*k];
            qs[wave][lane + 64*k] = v;
            qsq = fma((double)v, (double)v, qsq);
        }
        for (int off = 32; off; off >>= 1) qsq += __shfl_xor(qsq, off, 64);

        const double* pTb = pT64 + (size_t)b * D_ * C_;
        double a0 = 0.0, a1 = 0.0, a0b = 0.0, a1b = 0.0;
        #pragma unroll 4
        for (int d = 0; d < D_; d += 2) {
            double q0 = (double)qs[wave][d];
            double q1 = (double)qs[wave][d + 1];
            a0  = fma(pTb[(size_t)d*C_ + lane],            q0, a0);
            a1  = fma(pTb[(size_t)d*C_ + lane + 64],       q0, a1);
            a0b = fma(pTb[(size_t)(d + 1)*C_ + lane],      q1, a0b);
            a1b = fma(pTb[(size_t)(d + 1)*C_ + lane + 64], q1, a1b);
        }
        double dl0 = psq64[b*C_ + lane]      + qsq - 2.0*(a0 + a0b);
        double dl1 = psq64[b*C_ + lane + 64] + qsq - 2.0*(a1 + a1b);

        double bd; int bc;
        if (dl1 < dl0) { bd = dl1; bc = lane + 64; } else { bd = dl0; bc = lane; }
        for (int off = 32; off; off >>= 1) {
            double od = __shfl_xor(bd, off, 64);
            int    oc = __shfl_xor(bc, off, 64);
            if (od < bd || (od == bd && oc < bc)) { bd = od; bc = oc; }
        }
        if (lane == 0) {
            int tq = qtgt[gq];
            int oldc = (int)out_pred[gq];
            if (oldc != bc) {
                out_pred[gq] = (float)bc;
                int delta = ((bc == tq) ? 1 : 0) - ((oldc == tq) ? 1 : 0);
                if (delta) atomicAdd(acc_delta, delta);
            }
        }
    }
}

// ---------------- K4: finalize loss + accuracy ----------------
__global__ __launch_bounds__(256) void finalize_kernel(
    const double* __restrict__ blk_loss, const float* __restrict__ blk_acc,
    const int* __restrict__ acc_delta, float* __restrict__ out)
{
    __shared__ double rl[256];
    __shared__ float  ra[256];
    int tid = threadIdx.x;
    double s = 0.0; float a = 0.0f;
    for (int i = tid; i < 2048; i += 256) { s += blk_loss[i]; a += blk_acc[i]; }
    rl[tid] = s; ra[tid] = a;
    __syncthreads();
    for (int st = 128; st; st >>= 1) {
        if (tid < st) { rl[tid] += rl[tid + st]; ra[tid] += ra[tid + st]; }
        __syncthreads();
    }
    if (tid == 0) {
        out[B_*NQ_    ] = (float)(rl[0] / (double)(B_*NQ_));
        out[B_*NQ_ + 1] = (ra[0] + (float)(*acc_delta)) / (float)(B_*NQ_);
    }
}

extern "C" void kernel_launch(void* const* d_in, const int* in_sizes, int n_in,
                              void* d_out, int out_size, void* d_ws, size_t ws_size,
                              hipStream_t stream) {
    const float* sup  = (const float*)d_in[0];
    const float* qry  = (const float*)d_in[1];
    const int*   stgt = (const int*)d_in[2];
    const int*   qtgt = (const int*)d_in[3];
    float* out = (float*)d_out;

    char* ws = (char*)d_ws;
    constexpr size_t O_PART  = 0;                                // 32 MiB
    constexpr size_t O_PCNT  = O_PART  + (size_t)1024*8*512*8;   // 32 KiB
    constexpr size_t O_PT64  = O_PCNT  + (size_t)1024*8*4;       // 8 MiB
    constexpr size_t O_PF32  = O_PT64  + (size_t)B_*D_*C_*8;     // 4 MiB
    constexpr size_t O_PSQ64 = O_PF32  + (size_t)B_*C_*D_*4;     // 16 KiB
    constexpr size_t O_PSQ32 = O_PSQ64 + (size_t)B_*C_*8;        // 8 KiB
    constexpr size_t O_BLOSS = O_PSQ32 + (size_t)B_*C_*4;        // 16 KiB
    constexpr size_t O_BACC  = O_BLOSS + (size_t)2048*8;         // 8 KiB
    constexpr size_t O_FLAGS = O_BACC  + (size_t)2048*4;         // 256 KiB
    constexpr size_t O_CNTRS = O_FLAGS + (size_t)65536*4;        // 8 B

    double* part_sums = (double*)(ws + O_PART);
    int*    part_cnt  = (int*)   (ws + O_PCNT);
    double* pT64      = (double*)(ws + O_PT64);
    float*  pf32      = (float*) (ws + O_PF32);
    double* psq64     = (double*)(ws + O_PSQ64);
    float*  psq32     = (float*) (ws + O_PSQ32);
    double* blk_loss  = (double*)(ws + O_BLOSS);
    float*  blk_acc   = (float*) (ws + O_BACC);
    int*    flags     = (int*)   (ws + O_FLAGS);
    int*    flag_count= (int*)   (ws + O_CNTRS);
    int*    acc_delta = flag_count + 1;

    hipLaunchKernelGGL(proto_partial_kernel, dim3(1024), dim3(256), 0, stream,
                       sup, stgt, part_sums, part_cnt);
    hipLaunchKernelGGL(proto_reduce_kernel, dim3(2048), dim3(256), 0, stream,
                       part_sums, part_cnt, pT64, pf32, psq64, psq32, flag_count, acc_delta);
    hipLaunchKernelGGL(screen_kernel, dim3(2048), dim3(256), 0, stream,
                       qry, qtgt, pf32, psq32, out, blk_loss, blk_acc, flags, flag_count);
    hipLaunchKernelGGL(rescue_kernel, dim3(256), dim3(256), 0, stream,
                       qry, qtgt, pT64, psq64, flags, flag_count, out, acc_delta);
    hipLaunchKernelGGL(finalize_kernel, dim3(1), dim3(256), 0, stream,
                       blk_loss, blk_acc, acc_delta, out);
}